// Round 10
// baseline (209.059 us; speedup 1.0000x reference)
//
#include <hip/hip_runtime.h>
#include <float.h>
#include <stdint.h>

// Forbid FMA contraction: reference (numpy fp32) rounds every mul/add
// separately; a fused (a1+a2)-iw*ih could flip an iou>0.5 decision.
#pragma clang fp contract(off)

typedef unsigned long long ull;

#define NEGV   (-1e9f)
#define THRV   (0.05f)
#define MAXDET 100
#define NB     1152        // score buckets
#define BKBASE 31385       // (bits(0.05f) >> 15)
#define SLABSZ 1024        // LDS chunk capacity
#define CHTGT  512         // target head-chunk size
#define TKCAP  1024        // LDS-resident topk candidates; overflow -> global
#define BT     512

__device__ __forceinline__ int bktOf(unsigned u) {
  int v = (int)(u >> 15) - BKBASE;          // monotone in float for s > 0
  return v < 0 ? 0 : (v > NB - 1 ? NB - 1 : v);
}

// Bit-exact "(iou > 0.5)" decision. Certain cases via the two-sided window
// (margin 1e-5 >> max rounding error); ambiguous window does the exact
// reference IEEE divide.
__device__ __forceinline__ bool killpair(
    float qx1, float qy1, float qx2, float qy2, float qa,
    float x1, float y1, float x2, float y2, float a)
{
  const float iw = fminf(qx2, x2) - fmaxf(qx1, x1);
  const float ih = fminf(qy2, y2) - fmaxf(qy1, y1);
  if (iw <= 0.f || ih <= 0.f) return false;
  const float inter = iw * ih;
  const float den = fmaxf((qa + a) - inter, 1e-8f);
  const float i2 = inter + inter;
  if (i2 > den * 1.00001f) return true;
  if (i2 < den * 0.99999f) return false;
  return (inter / den) > 0.5f;
}

// suffix-sum of hist[] (descending bucket layout): hist[bk] becomes the count
// of elements in buckets STRICTLY ABOVE bk. Returns total. Ends barriered.
__device__ __forceinline__ int suffix_scan(int* hist, int* wtot,
                                           int tid, int lane, int wid) {
  int c0 = 0, c1 = 0, c2 = 0;
  if (tid < NB / 3) {
    c0 = hist[NB - 1 - 3 * tid];
    c1 = hist[NB - 2 - 3 * tid];
    c2 = hist[NB - 3 - 3 * tid];
  }
  const int tsum = c0 + c1 + c2;
  int inc = tsum;
#pragma unroll
  for (int off = 1; off < 64; off <<= 1) {
    const int u = __shfl_up(inc, off, 64);
    if (lane >= off) inc += u;
  }
  if (lane == 63) wtot[wid] = inc;
  __syncthreads();
  int wbase = 0, tot = 0;
#pragma unroll
  for (int w = 0; w < BT / 64; ++w) {
    const int v = wtot[w];
    if (w < wid) wbase += v;
    tot += v;
  }
  const int excl = wbase + inc - tsum;
  if (tid < NB / 3) {
    hist[NB - 1 - 3 * tid] = excl;
    hist[NB - 2 - 3 * tid] = excl + c0;
    hist[NB - 3 - 3 * tid] = excl + c0 + c1;
  }
  __syncthreads();
  return tot;
}

// Batched sorted scan: keep candidate iff no previously-kept box IoU>0.5.
// keys (LDS) descending (score desc, orig idx asc). Returns nk.
__device__ int run_scan(const ull* keys, int cn,
                        const float4* boxPre,
                        float4* kboxS, float* kscoreS, float* kareaS,
                        ull* wkill, ull* killby,
                        int tid, int lane, int wid)
{
#pragma clang fp contract(off)
  constexpr int NW = BT / 64;
  constexpr int CPW = 64 / NW;
  int nk = 0;
  for (int base = 0; base < cn && nk < MAXDET; base += 64) {
    const int nc = min(64, cn - base);
    const bool valid = lane < nc;
    const int p = base + lane;
    ull key = 0ull;
    if (valid) key = keys[p];
    const float score = __uint_as_float((unsigned)(key >> 32));
    float4 bx = make_float4(0.f, 0.f, 0.f, 0.f);
    if (valid) bx = boxPre[p];
    const float area = (bx.z - bx.x) * (bx.w - bx.y);

    // vs already-kept: wave w checks kept entries w, w+NW, ...
    bool kill = false;
    for (int e = wid; e < nk; e += NW) {
      const float4 q = kboxS[e];
      kill = kill || killpair(q.x, q.y, q.z, q.w, kareaS[e],
                              bx.x, bx.y, bx.z, bx.w, area);
    }
    {
      const ull bm = __ballot(valid && kill);
      if (lane == 0) wkill[wid] = bm;
    }
    // in-batch 64x64 matrix: wave w computes columns j = CPW*w .. +CPW-1
    {
      const int cb = wid * CPW;
#pragma unroll
      for (int jj = 0; jj < CPW; ++jj) {
        const int j = cb + jj;
        if (j < nc) {
          const float jx1 = __int_as_float(__builtin_amdgcn_readlane(__float_as_int(bx.x), j));
          const float jy1 = __int_as_float(__builtin_amdgcn_readlane(__float_as_int(bx.y), j));
          const float jx2 = __int_as_float(__builtin_amdgcn_readlane(__float_as_int(bx.z), j));
          const float jy2 = __int_as_float(__builtin_amdgcn_readlane(__float_as_int(bx.w), j));
          const float ja  = __int_as_float(__builtin_amdgcn_readlane(__float_as_int(area), j));
          const bool kij = valid && killpair(jx1, jy1, jx2, jy2, ja,
                                             bx.x, bx.y, bx.z, bx.w, area);
          const ull bm = __ballot(kij);
          if (lane == 0) killby[j] = bm;
        }
      }
    }
    __syncthreads();                      // wkill/killby ready

    ull kmask = 0;
#pragma unroll
    for (int w = 0; w < NW; ++w) kmask |= wkill[w];
    ull alive = ~kmask;
    alive &= (nc >= 64) ? ~0ull : ((1ull << nc) - 1ull);
    const ull kb = killby[lane];
    for (int j = 0; j < 64; ++j) {
      if ((alive >> j) & 1ull) {
        const unsigned klo = (unsigned)__builtin_amdgcn_readlane((int)(unsigned)kb, j);
        const unsigned khi = (unsigned)__builtin_amdgcn_readlane((int)(unsigned)(kb >> 32), j);
        const ull km = ((ull)khi << 32) | klo;
        alive &= ~(km & ((~1ull) << j));  // kill only lower-score bits
      }
    }
    if (wid == 0) {
      const int rank = (int)__popcll(alive & ((1ull << lane) - 1ull));
      if (((alive >> lane) & 1ull) && (nk + rank < MAXDET)) {
        kboxS[nk + rank] = bx;
        kscoreS[nk + rank] = score;
        kareaS[nk + rank] = area;
      }
    }
    nk += min((int)__popcll(alive), MAXDET - nk);
    __syncthreads();
  }
  return nk;
}

// Monotone-cursor selection tail re-scanning the score column (stride 1 for
// clsT, C for raw cls). Slow correctness path; never runs at bench stats.
__device__ int selection_tail(const float* __restrict__ col, int N, int stride,
                              ull lastKey, int nk,
                              const float4* __restrict__ bb4,
                              float4* kboxS, float* kscoreS, float* kareaS,
                              ull* redS, int* flagS,
                              int tid, int lane, int wid)
{
#pragma clang fp contract(off)
  while (nk < MAXDET) {
    ull best = 0ull;
    for (int i = tid; i < N; i += BT) {
      const float s = col[(size_t)i * stride];
      if (s > THRV) {
        const ull k = ((ull)__float_as_uint(s) << 32) | (unsigned)(~i);
        if (k < lastKey && k > best) best = k;
      }
    }
#pragma unroll
    for (int off = 32; off >= 1; off >>= 1) {
      const ull o = __shfl_xor(best, off, 64);
      if (o > best) best = o;
    }
    if (lane == 0) redS[wid] = best;
    if (tid == 0) *flagS = 0;
    __syncthreads();
    ull gbest = redS[0];
#pragma unroll
    for (int w = 1; w < BT / 64; ++w) if (redS[w] > gbest) gbest = redS[w];
    if (gbest == 0ull) break;            // exhausted (real keys are nonzero)
    const int idx = (int)(~(unsigned)gbest);
    const float4 q = bb4[idx];
    const float qa = (q.z - q.x) * (q.w - q.y);
    bool kl = false;
    for (int e = tid; e < nk; e += BT) {
      const float4 kq = kboxS[e];
      kl = kl || killpair(kq.x, kq.y, kq.z, kq.w, kareaS[e],
                          q.x, q.y, q.z, q.w, qa);
    }
    if (kl) atomicOr(flagS, 1);
    __syncthreads();
    const bool killed = (*flagS != 0);
    if (!killed) {
      if (tid == 0) {
        kboxS[nk] = q;
        kscoreS[nk] = __uint_as_float((unsigned)(gbest >> 32));
        kareaS[nk] = qa;
      }
      ++nk;
    }
    __syncthreads();
    lastKey = gbest;
  }
  return nk;
}

__device__ __forceinline__ unsigned agent_load_u32(const float* p) {
  return __hip_atomic_load((const unsigned*)p, __ATOMIC_RELAXED,
                           __HIP_MEMORY_SCOPE_AGENT);
}

// ---------------------------------------------------------------------------
// Single fused kernel, one block per (image, class):
//   Phase 1: all blocks cooperatively tile-transpose cls -> clsT (coalesced),
//            then a manual grid barrier (agent-scope counter + spin; safe:
//            grid <= 256 blocks, 1 CU each, all co-resident).
//   Phase 2: per-class head-select NMS on the contiguous clsT column
//            (float4 passes) -> rank sort -> batched sorted scan -> emit.
//   Phase 3: last block per image runs the per-image top-100 radix select.
// ---------------------------------------------------------------------------
__global__ __launch_bounds__(BT, 1) void nms_fused(
    const float* __restrict__ boxes, const float* __restrict__ cls,
    float* __restrict__ clsT, float* __restrict__ ksc, float* __restrict__ kbx,
    ull* __restrict__ gcand, unsigned* __restrict__ ctrs,
    float* __restrict__ out, int N, int C, int B)
{
#pragma clang fp contract(off)
  const int bc = blockIdx.x;
  const int b = bc / C, c = bc % C;
  const int tid = threadIdx.x, lane = tid & 63, wid = tid >> 6;
  const float4* bb4 = (const float4*)(boxes + (size_t)b * N * 4);

  __shared__ float tile[32][33];
  __shared__ int hist[NB];
  __shared__ int wtot[BT / 64];
  __shared__ ull slab[SLABSZ];
  __shared__ ull sorted[SLABSZ];              // reused as topk candidate slab
  __shared__ float4 boxPre[SLABSZ];
  __shared__ float4 kboxS[MAXDET];
  __shared__ float kscoreS[MAXDET], kareaS[MAXDET];
  __shared__ ull wkill[BT / 64], killby[64], redS[BT / 64];
  __shared__ int flagS, bkLoS, tBs, cposS, lastS;

  // ---- Phase 1: cooperative transpose + grid barrier (guarded) ----
  const bool useT = (gridDim.x <= 256);   // co-residency guaranteed
  if (useT) {
    const int ntC = (C + 31) / 32, ntN = (N + 31) / 32;
    const int ntot = B * ntN * ntC;
    const int tx = tid & 31, ty = tid >> 5;          // 32 x 16
    for (int t = blockIdx.x; t < ntot; t += gridDim.x) {
      const int ct = t % ntC;
      const int nt = (t / ntC) % ntN;
      const int tb = t / (ntC * ntN);
#pragma unroll
      for (int r = ty; r < 32; r += 16) {
        const int n = nt * 32 + r, cc = ct * 32 + tx;
        if (n < N && cc < C) tile[r][tx] = cls[((size_t)tb * N + n) * C + cc];
      }
      __syncthreads();
#pragma unroll
      for (int r = ty; r < 32; r += 16) {
        const int cc = ct * 32 + r, n = nt * 32 + tx;
        if (n < N && cc < C) clsT[((size_t)tb * C + cc) * N + n] = tile[tx][r];
      }
      __syncthreads();
    }
    __threadfence();                       // release clsT writes to agent
    __syncthreads();
    if (tid == 0) {
      __hip_atomic_fetch_add(&ctrs[0], 1u, __ATOMIC_ACQ_REL,
                             __HIP_MEMORY_SCOPE_AGENT);
      while (__hip_atomic_load(&ctrs[0], __ATOMIC_ACQUIRE,
                               __HIP_MEMORY_SCOPE_AGENT) < gridDim.x)
        __builtin_amdgcn_s_sleep(2);
    }
    __syncthreads();
    __threadfence();                       // acquire: invalidate stale L1
  }

  // ---- Phase 2: per-class NMS ----
  const float* colS = useT ? (clsT + (size_t)bc * N)
                           : (cls + (size_t)b * N * C + c);
  const int stride = useT ? 1 : C;
  const bool vec4 = (stride == 1) && ((((size_t)colS) & 15) == 0);
  const int nv4 = vec4 ? (N >> 2) : 0;
  const float4* col4 = (const float4*)colS;

  for (int i = tid; i < NB; i += BT) hist[i] = 0;
  if (tid == 0) bkLoS = -1;
  __syncthreads();
  // hist pass
  if (vec4) {
    for (int i = tid; i < nv4; i += BT) {
      const float4 v = col4[i];
      if (v.x > THRV) atomicAdd(&hist[bktOf(__float_as_uint(v.x))], 1);
      if (v.y > THRV) atomicAdd(&hist[bktOf(__float_as_uint(v.y))], 1);
      if (v.z > THRV) atomicAdd(&hist[bktOf(__float_as_uint(v.z))], 1);
      if (v.w > THRV) atomicAdd(&hist[bktOf(__float_as_uint(v.w))], 1);
    }
    for (int i = (nv4 << 2) + tid; i < N; i += BT) {
      const float s = colS[i];
      if (s > THRV) atomicAdd(&hist[bktOf(__float_as_uint(s))], 1);
    }
  } else {
    for (int i = tid; i < N; i += BT) {
      const float s = colS[(size_t)i * stride];
      if (s > THRV) atomicAdd(&hist[bktOf(__float_as_uint(s))], 1);
    }
  }
  __syncthreads();
  const int cn = suffix_scan(hist, wtot, tid, lane, wid);
  for (int bk = tid; bk < NB; bk += BT)
    if (hist[bk] >= CHTGT) atomicMax(&bkLoS, bk);
  __syncthreads();
  const int bkLo = bkLoS;
  const int chunkCnt = (bkLo >= 0) ? hist[bkLo] : cn;   // head is a prefix

  int nk = 0;
  if (cn > 0) {
    if (chunkCnt <= SLABSZ) {
      // scatter head (buckets > bkLo)
      if (vec4) {
        for (int i = tid; i < nv4; i += BT) {
          const float4 v = col4[i];
          const float sv[4] = {v.x, v.y, v.z, v.w};
#pragma unroll
          for (int j = 0; j < 4; ++j) {
            if (sv[j] > THRV) {
              const unsigned u = __float_as_uint(sv[j]);
              const int bk = bktOf(u);
              if (bk > bkLo)
                slab[atomicAdd(&hist[bk], 1)] =
                    ((ull)u << 32) | (unsigned)(~(4 * i + j));
            }
          }
        }
        for (int i = (nv4 << 2) + tid; i < N; i += BT) {
          const float s = colS[i];
          if (s > THRV) {
            const unsigned u = __float_as_uint(s);
            const int bk = bktOf(u);
            if (bk > bkLo)
              slab[atomicAdd(&hist[bk], 1)] = ((ull)u << 32) | (unsigned)(~i);
          }
        }
      } else {
        for (int i = tid; i < N; i += BT) {
          const float s = colS[(size_t)i * stride];
          if (s > THRV) {
            const unsigned u = __float_as_uint(s);
            const int bk = bktOf(u);
            if (bk > bkLo)
              slab[atomicAdd(&hist[bk], 1)] = ((ull)u << 32) | (unsigned)(~i);
          }
        }
      }
      __syncthreads();
      // rank-by-count sort (keys unique; broadcast LDS reads)
      for (int e = tid; e < chunkCnt; e += BT) {
        const ull k = slab[e];
        int r = 0;
        for (int j = 0; j < chunkCnt; ++j) r += (slab[j] > k) ? 1 : 0;
        sorted[r] = k;
      }
      __syncthreads();
      for (int e = tid; e < chunkCnt; e += BT)
        boxPre[e] = bb4[(int)(~(unsigned)sorted[e])];
      __syncthreads();
      nk = run_scan(sorted, chunkCnt, boxPre,
                    kboxS, kscoreS, kareaS, wkill, killby, tid, lane, wid);
      if (nk < MAXDET && chunkCnt < cn)
        nk = selection_tail(colS, N, stride, sorted[chunkCnt - 1], nk, bb4,
                            kboxS, kscoreS, kareaS, redS, &flagS,
                            tid, lane, wid);
    } else {
      // degenerate (giant single bucket): full selection from scratch
      nk = selection_tail(colS, N, stride, ~0ull, 0, bb4,
                          kboxS, kscoreS, kareaS, redS, &flagS,
                          tid, lane, wid);
    }
  }

  // ---- emit kept list ----
  float* ko  = ksc + (size_t)bc * MAXDET;
  float* kbo = kbx + (size_t)bc * MAXDET * 4;
  for (int e = tid; e < MAXDET; e += BT) {
    if (e < nk) {
      const float4 q = kboxS[e];
      ko[e] = kscoreS[e];
      kbo[e * 4 + 0] = q.x; kbo[e * 4 + 1] = q.y;
      kbo[e * 4 + 2] = q.z; kbo[e * 4 + 3] = q.w;
    } else {
      ko[e] = NEGV;
      kbo[e * 4 + 0] = 0.f; kbo[e * 4 + 1] = 0.f;
      kbo[e * 4 + 2] = 0.f; kbo[e * 4 + 3] = 0.f;
    }
  }

  // ---- Phase 3 handshake: last block of image b runs topk ----
  __threadfence();
  __syncthreads();
  if (tid == 0) {
    const unsigned old = __hip_atomic_fetch_add(
        &ctrs[1 + b], 1u, __ATOMIC_ACQ_REL, __HIP_MEMORY_SCOPE_AGENT);
    lastS = (old == (unsigned)(C - 1)) ? 1 : 0;
  }
  __syncthreads();
  if (!lastS) return;

  // ======================= per-image top-100 =======================
  const int T = C * MAXDET;
  const float* s0 = ksc + (size_t)b * T;
  ull* gc = gcand + (size_t)b * T;              // overflow only
  float* ob = out;                              // [B][100][4]
  float* os = out + (size_t)B * MAXDET * 4;     // [B][100]
  float* ol = os + (size_t)B * MAXDET;          // [B][100] labels as float

  for (int i = tid; i < NB; i += BT) hist[i] = 0;
  if (tid == 0) { cposS = 0; tBs = 0; }
  __syncthreads();
  for (int f = tid; f < T; f += BT) {
    const unsigned u = agent_load_u32(&s0[f]);
    if (__uint_as_float(u) > THRV) atomicAdd(&hist[bktOf(u)], 1);
  }
  __syncthreads();
  suffix_scan(hist, wtot, tid, lane, wid);
  for (int bk = tid; bk < NB; bk += BT)
    if (hist[bk] < MAXDET && (bk == 0 || hist[bk - 1] >= MAXDET)) tBs = bk;
  __syncthreads();
  const int t = tBs;
  for (int f = tid; f < T; f += BT) {
    const unsigned u = agent_load_u32(&s0[f]);
    if (__uint_as_float(u) > THRV && bktOf(u) >= t) {
      const int p = atomicAdd(&cposS, 1);
      const ull key = ((ull)u << 32) | (unsigned)(~f);
      if (p < TKCAP) sorted[p] = key; else gc[p] = key;
    }
  }
  __syncthreads();
  const int nc = cposS;
  const int nw = min(nc, MAXDET);
  for (int s2 = nw + tid; s2 < MAXDET; s2 += BT) {
    float* od = ob + ((size_t)b * MAXDET + s2) * 4;
    od[0] = -1.f; od[1] = -1.f; od[2] = -1.f; od[3] = -1.f;
    os[(size_t)b * MAXDET + s2] = -1.f;
    ol[(size_t)b * MAXDET + s2] = -1.f;
  }
  for (int e = tid; e < nc; e += BT) {
    const ull k = (e < TKCAP) ? sorted[e] : gc[e];
    int rank = 0;
    for (int j = 0; j < nc; ++j) {
      const ull o = (j < TKCAP) ? sorted[j] : gc[j];
      rank += (o > k) ? 1 : 0;
    }
    if (rank < MAXDET) {
      const int f = (int)(~(unsigned)k);
      const float sc = __uint_as_float((unsigned)(k >> 32));
      const float* bp = kbx + ((size_t)b * T + f) * 4;
      float* od = ob + ((size_t)b * MAXDET + rank) * 4;
      od[0] = __uint_as_float(agent_load_u32(&bp[0]));
      od[1] = __uint_as_float(agent_load_u32(&bp[1]));
      od[2] = __uint_as_float(agent_load_u32(&bp[2]));
      od[3] = __uint_as_float(agent_load_u32(&bp[3]));
      os[(size_t)b * MAXDET + rank] = sc;
      ol[(size_t)b * MAXDET + rank] = (float)(f / MAXDET);
    }
  }
}

extern "C" void kernel_launch(void* const* d_in, const int* in_sizes, int n_in,
                              void* d_out, int out_size, void* d_ws, size_t ws_size,
                              hipStream_t stream) {
  const float* boxes = (const float*)d_in[0];  // (B, N, 4) f32
  const float* cls   = (const float*)d_in[1];  // (B, N, C) f32
  const int B = out_size / (MAXDET * 6);       // 4 box + 1 score + 1 label
  const int N = in_sizes[0] / (B * 4);
  const int C = in_sizes[1] / (B * N);

  char* ws = (char*)d_ws;
  float* clsT = (float*)ws; ws += (size_t)B * C * N * 4;       // transposed cls
  ull* gcand = (ull*)ws;    ws += (size_t)B * C * MAXDET * 8;  // topk overflow
  float* kbx = (float*)ws;  ws += (size_t)B * C * MAXDET * 16; // kept boxes
  float* ksc = (float*)ws;  ws += (size_t)B * C * MAXDET * 4;  // kept scores
  unsigned* ctrs = (unsigned*)ws;                              // [0]=xpose, [1+b]=done

  hipMemsetAsync(ctrs, 0, (size_t)(1 + B) * 4, stream);
  nms_fused<<<dim3(B * C), dim3(BT), 0, stream>>>(
      boxes, cls, clsT, ksc, kbx, gcand, ctrs, (float*)d_out, N, C, B);
}

// Round 11
// 145.041 us; speedup vs baseline: 1.4414x; 1.4414x over previous
//
#include <hip/hip_runtime.h>
#include <float.h>
#include <stdint.h>

// Forbid FMA contraction: reference (numpy fp32) rounds every mul/add
// separately; a fused (a1+a2)-iw*ih could flip an iou>0.5 decision.
#pragma clang fp contract(off)

typedef unsigned long long ull;

#define NEGV   (-1e9f)
#define THRV   (0.05f)
#define MAXDET 100
#define NB     1152        // score buckets
#define BKBASE 31385       // (bits(0.05f) >> 15)
#define SLABSZ 1024        // LDS chunk capacity
#define CHTGT  256         // target head-chunk size (>=2.3x the ~107 consumed)
#define TKCAP  1024        // LDS-resident topk candidates; overflow -> global
#define BT     512

__device__ __forceinline__ int bktOf(unsigned u) {
  int v = (int)(u >> 15) - BKBASE;          // monotone in float for s > 0
  return v < 0 ? 0 : (v > NB - 1 ? NB - 1 : v);
}

// Bit-exact "(iou > 0.5)" decision. Certain cases via the two-sided window
// (margin 1e-5 >> max rounding error); ambiguous window does the exact
// reference IEEE divide.
__device__ __forceinline__ bool killpair(
    float qx1, float qy1, float qx2, float qy2, float qa,
    float x1, float y1, float x2, float y2, float a)
{
  const float iw = fminf(qx2, x2) - fmaxf(qx1, x1);
  const float ih = fminf(qy2, y2) - fmaxf(qy1, y1);
  if (iw <= 0.f || ih <= 0.f) return false;
  const float inter = iw * ih;
  const float den = fmaxf((qa + a) - inter, 1e-8f);
  const float i2 = inter + inter;
  if (i2 > den * 1.00001f) return true;
  if (i2 < den * 0.99999f) return false;
  return (inter / den) > 0.5f;
}

// suffix-sum of hist[] (descending bucket layout): hist[bk] becomes the count
// of elements in buckets STRICTLY ABOVE bk. Returns total. Ends barriered.
__device__ __forceinline__ int suffix_scan(int* hist, int* wtot,
                                           int tid, int lane, int wid) {
  int c0 = 0, c1 = 0, c2 = 0;
  if (tid < NB / 3) {
    c0 = hist[NB - 1 - 3 * tid];
    c1 = hist[NB - 2 - 3 * tid];
    c2 = hist[NB - 3 - 3 * tid];
  }
  const int tsum = c0 + c1 + c2;
  int inc = tsum;
#pragma unroll
  for (int off = 1; off < 64; off <<= 1) {
    const int u = __shfl_up(inc, off, 64);
    if (lane >= off) inc += u;
  }
  if (lane == 63) wtot[wid] = inc;
  __syncthreads();
  int wbase = 0, tot = 0;
#pragma unroll
  for (int w = 0; w < BT / 64; ++w) {
    const int v = wtot[w];
    if (w < wid) wbase += v;
    tot += v;
  }
  const int excl = wbase + inc - tsum;
  if (tid < NB / 3) {
    hist[NB - 1 - 3 * tid] = excl;
    hist[NB - 2 - 3 * tid] = excl + c0;
    hist[NB - 3 - 3 * tid] = excl + c0 + c1;
  }
  __syncthreads();
  return tot;
}

// Batched sorted scan: keep candidate iff no previously-kept box IoU>0.5.
// keys (LDS) descending (score desc, orig idx asc). Returns nk.
__device__ int run_scan(const ull* keys, int cn,
                        const float4* boxPre,
                        float4* kboxS, float* kscoreS, float* kareaS,
                        ull* wkill, ull* killby,
                        int tid, int lane, int wid)
{
#pragma clang fp contract(off)
  constexpr int NW = BT / 64;
  constexpr int CPW = 64 / NW;
  int nk = 0;
  for (int base = 0; base < cn && nk < MAXDET; base += 64) {
    const int nc = min(64, cn - base);
    const bool valid = lane < nc;
    const int p = base + lane;
    ull key = 0ull;
    if (valid) key = keys[p];
    const float score = __uint_as_float((unsigned)(key >> 32));
    float4 bx = make_float4(0.f, 0.f, 0.f, 0.f);
    if (valid) bx = boxPre[p];
    const float area = (bx.z - bx.x) * (bx.w - bx.y);

    // vs already-kept: wave w checks kept entries w, w+NW, ...
    bool kill = false;
    for (int e = wid; e < nk; e += NW) {
      const float4 q = kboxS[e];
      kill = kill || killpair(q.x, q.y, q.z, q.w, kareaS[e],
                              bx.x, bx.y, bx.z, bx.w, area);
    }
    {
      const ull bm = __ballot(valid && kill);
      if (lane == 0) wkill[wid] = bm;
    }
    // in-batch 64x64 matrix: wave w computes columns j = CPW*w .. +CPW-1
    {
      const int cb = wid * CPW;
#pragma unroll
      for (int jj = 0; jj < CPW; ++jj) {
        const int j = cb + jj;
        if (j < nc) {
          const float jx1 = __int_as_float(__builtin_amdgcn_readlane(__float_as_int(bx.x), j));
          const float jy1 = __int_as_float(__builtin_amdgcn_readlane(__float_as_int(bx.y), j));
          const float jx2 = __int_as_float(__builtin_amdgcn_readlane(__float_as_int(bx.z), j));
          const float jy2 = __int_as_float(__builtin_amdgcn_readlane(__float_as_int(bx.w), j));
          const float ja  = __int_as_float(__builtin_amdgcn_readlane(__float_as_int(area), j));
          const bool kij = valid && killpair(jx1, jy1, jx2, jy2, ja,
                                             bx.x, bx.y, bx.z, bx.w, area);
          const ull bm = __ballot(kij);
          if (lane == 0) killby[j] = bm;
        }
      }
    }
    __syncthreads();                      // wkill/killby ready

    ull kmask = 0;
#pragma unroll
    for (int w = 0; w < NW; ++w) kmask |= wkill[w];
    ull alive = ~kmask;
    alive &= (nc >= 64) ? ~0ull : ((1ull << nc) - 1ull);
    const ull kb = killby[lane];
    for (int j = 0; j < 64; ++j) {
      if ((alive >> j) & 1ull) {
        const unsigned klo = (unsigned)__builtin_amdgcn_readlane((int)(unsigned)kb, j);
        const unsigned khi = (unsigned)__builtin_amdgcn_readlane((int)(unsigned)(kb >> 32), j);
        const ull km = ((ull)khi << 32) | klo;
        alive &= ~(km & ((~1ull) << j));  // kill only lower-score bits
      }
    }
    if (wid == 0) {
      const int rank = (int)__popcll(alive & ((1ull << lane) - 1ull));
      if (((alive >> lane) & 1ull) && (nk + rank < MAXDET)) {
        kboxS[nk + rank] = bx;
        kscoreS[nk + rank] = score;
        kareaS[nk + rank] = area;
      }
    }
    nk += min((int)__popcll(alive), MAXDET - nk);
    __syncthreads();
  }
  return nk;
}

// Monotone-cursor selection tail re-scanning the contiguous score column.
// Slow correctness path; never runs at bench stats.
__device__ int selection_tail(const float* __restrict__ col, int N,
                              ull lastKey, int nk,
                              const float4* __restrict__ bb4,
                              float4* kboxS, float* kscoreS, float* kareaS,
                              ull* redS, int* flagS,
                              int tid, int lane, int wid)
{
#pragma clang fp contract(off)
  while (nk < MAXDET) {
    ull best = 0ull;
    for (int i = tid; i < N; i += BT) {
      const float s = col[i];
      if (s > THRV) {
        const ull k = ((ull)__float_as_uint(s) << 32) | (unsigned)(~i);
        if (k < lastKey && k > best) best = k;
      }
    }
#pragma unroll
    for (int off = 32; off >= 1; off >>= 1) {
      const ull o = __shfl_xor(best, off, 64);
      if (o > best) best = o;
    }
    if (lane == 0) redS[wid] = best;
    if (tid == 0) *flagS = 0;
    __syncthreads();
    ull gbest = redS[0];
#pragma unroll
    for (int w = 1; w < BT / 64; ++w) if (redS[w] > gbest) gbest = redS[w];
    if (gbest == 0ull) break;            // exhausted (real keys are nonzero)
    const int idx = (int)(~(unsigned)gbest);
    const float4 q = bb4[idx];
    const float qa = (q.z - q.x) * (q.w - q.y);
    bool kl = false;
    for (int e = tid; e < nk; e += BT) {
      const float4 kq = kboxS[e];
      kl = kl || killpair(kq.x, kq.y, kq.z, kq.w, kareaS[e],
                          q.x, q.y, q.z, q.w, qa);
    }
    if (kl) atomicOr(flagS, 1);
    __syncthreads();
    const bool killed = (*flagS != 0);
    if (!killed) {
      if (tid == 0) {
        kboxS[nk] = q;
        kscoreS[nk] = __uint_as_float((unsigned)(gbest >> 32));
        kareaS[nk] = qa;
      }
      ++nk;
    }
    __syncthreads();
    lastKey = gbest;
  }
  return nk;
}

__device__ __forceinline__ unsigned agent_load_u32(const float* p) {
  return __hip_atomic_load((const unsigned*)p, __ATOMIC_RELAXED,
                           __HIP_MEMORY_SCOPE_AGENT);
}

// ---------------------------------------------------------------------------
// Kernel 0: cls (B,N,C) -> clsT (B,C,N), LDS-tiled, fully coalesced.
// (Kernel boundary provides the cross-XCD visibility for clsT.)
// ---------------------------------------------------------------------------
__global__ __launch_bounds__(256, 1) void transpose_kernel(
    const float* __restrict__ cls, float* __restrict__ clsT, int N, int C)
{
  __shared__ float tile[32][33];
  const int b = blockIdx.z;
  const int n0 = blockIdx.x * 32, c0 = blockIdx.y * 32;
  const int tx = threadIdx.x, ty = threadIdx.y;   // 32 x 8
#pragma unroll
  for (int r = ty; r < 32; r += 8) {
    const int n = n0 + r, c = c0 + tx;
    if (n < N && c < C) tile[r][tx] = cls[((size_t)b * N + n) * C + c];
  }
  __syncthreads();
#pragma unroll
  for (int r = ty; r < 32; r += 8) {
    const int c = c0 + r, n = n0 + tx;
    if (n < N && c < C) clsT[((size_t)b * C + c) * N + n] = tile[tx][r];
  }
}

// ---------------------------------------------------------------------------
// Kernel 1: one block per (image, class):
//   contiguous float4 column reads -> hist -> head-chunk radix select ->
//   rank-by-count sort -> box prefetch -> batched sorted scan -> emit.
//   Last-finishing block of each image runs the per-image top-100.
// ---------------------------------------------------------------------------
__global__ __launch_bounds__(BT, 1) void nms_fused(
    const float* __restrict__ boxes, const float* __restrict__ clsT,
    float* __restrict__ ksc, float* __restrict__ kbx,
    ull* __restrict__ gcand, unsigned* __restrict__ ctrs,
    float* __restrict__ out, int N, int C, int B)
{
#pragma clang fp contract(off)
  const int bc = blockIdx.x;
  const int b = bc / C;
  const int tid = threadIdx.x, lane = tid & 63, wid = tid >> 6;
  const float4* bb4 = (const float4*)(boxes + (size_t)b * N * 4);
  const float* colS = clsT + (size_t)bc * N;

  __shared__ int hist[NB];
  __shared__ int wtot[BT / 64];
  __shared__ ull slab[SLABSZ];
  __shared__ ull sorted[SLABSZ];              // reused as topk candidate slab
  __shared__ float4 boxPre[SLABSZ];
  __shared__ float4 kboxS[MAXDET];
  __shared__ float kscoreS[MAXDET], kareaS[MAXDET];
  __shared__ ull wkill[BT / 64], killby[64], redS[BT / 64];
  __shared__ int flagS, bkLoS, tBs, cposS, lastS;

  const bool vec4 = ((((size_t)colS) & 15) == 0);
  const int nv4 = vec4 ? (N >> 2) : 0;
  const float4* col4 = (const float4*)colS;

  for (int i = tid; i < NB; i += BT) hist[i] = 0;
  if (tid == 0) bkLoS = -1;
  __syncthreads();
  // ---- hist pass ----
  if (vec4) {
    for (int i = tid; i < nv4; i += BT) {
      const float4 v = col4[i];
      if (v.x > THRV) atomicAdd(&hist[bktOf(__float_as_uint(v.x))], 1);
      if (v.y > THRV) atomicAdd(&hist[bktOf(__float_as_uint(v.y))], 1);
      if (v.z > THRV) atomicAdd(&hist[bktOf(__float_as_uint(v.z))], 1);
      if (v.w > THRV) atomicAdd(&hist[bktOf(__float_as_uint(v.w))], 1);
    }
    for (int i = (nv4 << 2) + tid; i < N; i += BT) {
      const float s = colS[i];
      if (s > THRV) atomicAdd(&hist[bktOf(__float_as_uint(s))], 1);
    }
  } else {
    for (int i = tid; i < N; i += BT) {
      const float s = colS[i];
      if (s > THRV) atomicAdd(&hist[bktOf(__float_as_uint(s))], 1);
    }
  }
  __syncthreads();
  const int cn = suffix_scan(hist, wtot, tid, lane, wid);
  for (int bk = tid; bk < NB; bk += BT)
    if (hist[bk] >= CHTGT) atomicMax(&bkLoS, bk);
  __syncthreads();
  const int bkLo = bkLoS;
  const int chunkCnt = (bkLo >= 0) ? hist[bkLo] : cn;   // head is a prefix

  int nk = 0;
  if (cn > 0) {
    if (chunkCnt <= SLABSZ) {
      // ---- scatter head (buckets > bkLo) ----
      if (vec4) {
        for (int i = tid; i < nv4; i += BT) {
          const float4 v = col4[i];
          const float sv[4] = {v.x, v.y, v.z, v.w};
#pragma unroll
          for (int j = 0; j < 4; ++j) {
            if (sv[j] > THRV) {
              const unsigned u = __float_as_uint(sv[j]);
              const int bk = bktOf(u);
              if (bk > bkLo)
                slab[atomicAdd(&hist[bk], 1)] =
                    ((ull)u << 32) | (unsigned)(~(4 * i + j));
            }
          }
        }
        for (int i = (nv4 << 2) + tid; i < N; i += BT) {
          const float s = colS[i];
          if (s > THRV) {
            const unsigned u = __float_as_uint(s);
            const int bk = bktOf(u);
            if (bk > bkLo)
              slab[atomicAdd(&hist[bk], 1)] = ((ull)u << 32) | (unsigned)(~i);
          }
        }
      } else {
        for (int i = tid; i < N; i += BT) {
          const float s = colS[i];
          if (s > THRV) {
            const unsigned u = __float_as_uint(s);
            const int bk = bktOf(u);
            if (bk > bkLo)
              slab[atomicAdd(&hist[bk], 1)] = ((ull)u << 32) | (unsigned)(~i);
          }
        }
      }
      __syncthreads();
      // ---- rank-by-count sort (keys unique; broadcast LDS reads) ----
      for (int e = tid; e < chunkCnt; e += BT) {
        const ull k = slab[e];
        int r = 0;
        for (int j = 0; j < chunkCnt; ++j) r += (slab[j] > k) ? 1 : 0;
        sorted[r] = k;
      }
      __syncthreads();
      for (int e = tid; e < chunkCnt; e += BT)
        boxPre[e] = bb4[(int)(~(unsigned)sorted[e])];
      __syncthreads();
      nk = run_scan(sorted, chunkCnt, boxPre,
                    kboxS, kscoreS, kareaS, wkill, killby, tid, lane, wid);
      if (nk < MAXDET && chunkCnt < cn)
        nk = selection_tail(colS, N, sorted[chunkCnt - 1], nk, bb4,
                            kboxS, kscoreS, kareaS, redS, &flagS,
                            tid, lane, wid);
    } else {
      // degenerate (giant single bucket): full selection from scratch
      nk = selection_tail(colS, N, ~0ull, 0, bb4,
                          kboxS, kscoreS, kareaS, redS, &flagS,
                          tid, lane, wid);
    }
  }

  // ---- emit kept list ----
  float* ko  = ksc + (size_t)bc * MAXDET;
  float* kbo = kbx + (size_t)bc * MAXDET * 4;
  for (int e = tid; e < MAXDET; e += BT) {
    if (e < nk) {
      const float4 q = kboxS[e];
      ko[e] = kscoreS[e];
      kbo[e * 4 + 0] = q.x; kbo[e * 4 + 1] = q.y;
      kbo[e * 4 + 2] = q.z; kbo[e * 4 + 3] = q.w;
    } else {
      ko[e] = NEGV;
      kbo[e * 4 + 0] = 0.f; kbo[e * 4 + 1] = 0.f;
      kbo[e * 4 + 2] = 0.f; kbo[e * 4 + 3] = 0.f;
    }
  }

  // ---- handshake: last block of image b runs topk ----
  __threadfence();
  __syncthreads();
  if (tid == 0) {
    const unsigned old = __hip_atomic_fetch_add(
        &ctrs[b], 1u, __ATOMIC_ACQ_REL, __HIP_MEMORY_SCOPE_AGENT);
    lastS = (old == (unsigned)(C - 1)) ? 1 : 0;
  }
  __syncthreads();
  if (!lastS) return;

  // ======================= per-image top-100 =======================
  const int T = C * MAXDET;
  const float* s0 = ksc + (size_t)b * T;
  ull* gc = gcand + (size_t)b * T;              // overflow only
  float* ob = out;                              // [B][100][4]
  float* os = out + (size_t)B * MAXDET * 4;     // [B][100]
  float* ol = os + (size_t)B * MAXDET;          // [B][100] labels as float

  for (int i = tid; i < NB; i += BT) hist[i] = 0;
  if (tid == 0) { cposS = 0; tBs = 0; }
  __syncthreads();
  for (int f = tid; f < T; f += BT) {
    const unsigned u = agent_load_u32(&s0[f]);
    if (__uint_as_float(u) > THRV) atomicAdd(&hist[bktOf(u)], 1);
  }
  __syncthreads();
  suffix_scan(hist, wtot, tid, lane, wid);
  for (int bk = tid; bk < NB; bk += BT)
    if (hist[bk] < MAXDET && (bk == 0 || hist[bk - 1] >= MAXDET)) tBs = bk;
  __syncthreads();
  const int t = tBs;
  for (int f = tid; f < T; f += BT) {
    const unsigned u = agent_load_u32(&s0[f]);
    if (__uint_as_float(u) > THRV && bktOf(u) >= t) {
      const int p = atomicAdd(&cposS, 1);
      const ull key = ((ull)u << 32) | (unsigned)(~f);
      if (p < TKCAP) sorted[p] = key; else gc[p] = key;
    }
  }
  __syncthreads();
  const int nc = cposS;
  const int nw = min(nc, MAXDET);
  for (int s2 = nw + tid; s2 < MAXDET; s2 += BT) {
    float* od = ob + ((size_t)b * MAXDET + s2) * 4;
    od[0] = -1.f; od[1] = -1.f; od[2] = -1.f; od[3] = -1.f;
    os[(size_t)b * MAXDET + s2] = -1.f;
    ol[(size_t)b * MAXDET + s2] = -1.f;
  }
  for (int e = tid; e < nc; e += BT) {
    const ull k = (e < TKCAP) ? sorted[e] : gc[e];
    int rank = 0;
    for (int j = 0; j < nc; ++j) {
      const ull o = (j < TKCAP) ? sorted[j] : gc[j];
      rank += (o > k) ? 1 : 0;
    }
    if (rank < MAXDET) {
      const int f = (int)(~(unsigned)k);
      const float sc = __uint_as_float((unsigned)(k >> 32));
      const float* bp = kbx + ((size_t)b * T + f) * 4;
      float* od = ob + ((size_t)b * MAXDET + rank) * 4;
      od[0] = __uint_as_float(agent_load_u32(&bp[0]));
      od[1] = __uint_as_float(agent_load_u32(&bp[1]));
      od[2] = __uint_as_float(agent_load_u32(&bp[2]));
      od[3] = __uint_as_float(agent_load_u32(&bp[3]));
      os[(size_t)b * MAXDET + rank] = sc;
      ol[(size_t)b * MAXDET + rank] = (float)(f / MAXDET);
    }
  }
}

extern "C" void kernel_launch(void* const* d_in, const int* in_sizes, int n_in,
                              void* d_out, int out_size, void* d_ws, size_t ws_size,
                              hipStream_t stream) {
  const float* boxes = (const float*)d_in[0];  // (B, N, 4) f32
  const float* cls   = (const float*)d_in[1];  // (B, N, C) f32
  const int B = out_size / (MAXDET * 6);       // 4 box + 1 score + 1 label
  const int N = in_sizes[0] / (B * 4);
  const int C = in_sizes[1] / (B * N);

  char* ws = (char*)d_ws;
  float* clsT = (float*)ws; ws += (size_t)B * C * N * 4;       // transposed cls
  ull* gcand = (ull*)ws;    ws += (size_t)B * C * MAXDET * 8;  // topk overflow
  float* kbx = (float*)ws;  ws += (size_t)B * C * MAXDET * 16; // kept boxes
  float* ksc = (float*)ws;  ws += (size_t)B * C * MAXDET * 4;  // kept scores
  unsigned* ctrs = (unsigned*)ws;                              // per-image done

  hipMemsetAsync(ctrs, 0, (size_t)B * 4, stream);
  transpose_kernel<<<dim3((N + 31) / 32, (C + 31) / 32, B), dim3(32, 8),
                     0, stream>>>(cls, clsT, N, C);
  nms_fused<<<dim3(B * C), dim3(BT), 0, stream>>>(
      boxes, clsT, ksc, kbx, gcand, ctrs, (float*)d_out, N, C, B);
}